// Round 7
// baseline (254.611 us; speedup 1.0000x reference)
//
#include <hip/hip_runtime.h>

#define G 4096
#define BSZ 2
#define NIN 8
#define HID 32
#define NLOG2E (-1.4426950408889634f)

typedef __attribute__((ext_vector_type(8))) short short8;
typedef __attribute__((ext_vector_type(4))) float floatx4;
typedef unsigned short ushort_t;
typedef unsigned int uint_t;

__device__ __forceinline__ float elu1(float v) {
    return v > 0.f ? v : (__expf(v) - 1.f);
}
__device__ __forceinline__ ushort_t f2bf(float f) {
    unsigned u = __float_as_uint(f);
    u += 0x7fffu + ((u >> 16) & 1u);
    return (ushort_t)(u >> 16);
}

// Combined setup + adjacency pre-pack kernel.
// Blocks 0..31: h = elu(x@W_infer+b), s_src/s_dst (pre-scaled by -log2e),
//               hT bf16 transpose.
// Blocks 32..4127: bit-pack edges1/edges2 (COALESCED: lane i reads float4 at
//               4i -> wave reads 1KB contiguous; 3x shfl_xor 8-lane merge).
__global__ __launch_bounds__(256) void k_pre(
    const float* __restrict__ x, const float* __restrict__ W,
    const float* __restrict__ bias, const float* __restrict__ We,
    float* __restrict__ h0, ushort_t* __restrict__ hTb,
    float* __restrict__ ssrc, float* __restrict__ sdst,
    const float* __restrict__ e1, const float* __restrict__ e2,
    uint_t* __restrict__ pk1, uint_t* __restrict__ pk2) {
    __shared__ __align__(16) ushort_t hs[HID][264];
    int tid = threadIdx.x;
    if (blockIdx.x >= 32) {
        // ---- adjacency pre-pack: 4096 blocks x 32 KB contiguous ----
        int pbi = (int)blockIdx.x - 32;
        const float* src = (pbi < 2048) ? e1 : e2;
        uint_t* dst = (pbi < 2048) ? pk1 : pk2;
        int pbm = pbi & 2047;
        const int lsh = (tid & 7) * 4;
        const bool st = (tid & 7) == 0;
#pragma unroll
        for (int it = 0; it < 8; ++it) {
            int f4 = pbm * 2048 + it * 256 + tid;    // float4 index
            float4 v4 = *((const float4*)src + f4);
            uint_t nib = (uint_t)(v4.x != 0.f) | ((uint_t)(v4.y != 0.f) << 1) |
                         ((uint_t)(v4.z != 0.f) << 2) | ((uint_t)(v4.w != 0.f) << 3);
            uint_t wd = nib << lsh;
            wd |= __shfl_xor(wd, 1);
            wd |= __shfl_xor(wd, 2);
            wd |= __shfl_xor(wd, 4);
            if (st) dst[f4 >> 3] = wd;
        }
        return;
    }
    // ---- setup: 32 blocks ----
    int t = blockIdx.x * 256 + tid;
    int b = t >> 12;
    int g0 = (blockIdx.x & 15) * 256;
    float xin[NIN];
    const float* xp = x + t * NIN;
#pragma unroll
    for (int k = 0; k < NIN; k++) xin[k] = xp[k];
    float ss = 0.f, sd = 0.f;
    float* hp = h0 + (size_t)t * HID;
#pragma unroll
    for (int o = 0; o < HID; o++) {
        float v = bias[o];
#pragma unroll
        for (int k = 0; k < NIN; k++) v += xin[k] * W[k * HID + o];
        v = elu1(v);
        hp[o] = v;
        hs[o][tid] = f2bf(v);
        ss += v * We[o];
        sd += v * We[HID + o];
    }
    ssrc[t] = ss * NLOG2E;   // pre-scaled: consumer uses exp2f directly
    sdst[t] = sd * NLOG2E;
    __syncthreads();
#pragma unroll
    for (int p = 0; p < 4; p++) {
        int row = p * 8 + (tid >> 5);
        int c = (tid & 31) * 8;
        short8 v8 = *(const short8*)&hs[row][c];
        *(short8*)(void*)&hTb[(size_t)(b * HID + row) * G + g0 + c] = v8;
    }
}

// Fully fused MP block: 16 genes x 2 batches per block, full j-range.
// 1024 threads = 16 waves (b x jq0..7). Adjacency comes PRE-PACKED as bits:
// staging = 2 coalesced dword loads/thread -> LDS transpose (padded, no
// conflicts). ssm staging is a pure copy (producer pre-scales). Compute:
// fully-unrolled 16-iter loop, hTb prefetch 4-deep, sv/bw 2-deep register
// prefetch; e->bf16 by truncation (es stays fp32-exact); 8-way LDS merge;
// node+merge MLP (+BN+proj+hT for layer 1) in-block.
template <bool DO_BN>
__global__ __launch_bounds__(1024, 4) void k_fused(
    const uint_t* __restrict__ pk, const float* __restrict__ ssrc,
    const float* __restrict__ sdst, const ushort_t* __restrict__ hTb_in,
    const float* __restrict__ bep, float coef, const float* __restrict__ hin,
    const float* __restrict__ Wn, const float* __restrict__ bnb,
    const float* __restrict__ Wm, const float* __restrict__ bmb,
    const float* __restrict__ gamma, const float* __restrict__ beta,
    const float* __restrict__ We2, float* __restrict__ outp,
    ushort_t* __restrict__ hTb_out, float* __restrict__ s2s,
    float* __restrict__ s2d) {
    union SMemU {
        float ssm[BSZ][G];                       // compute phase (32 KB)
        struct {                                 // post phase (~19.2 KB)
            float rec[32][68];
            float rec2[32][68];
            float esg[16][2];
            ushort_t tb[BSZ][HID][16];
        } p;
    };
    __shared__ __align__(16) SMemU sm;
    __shared__ __align__(16) uint_t abits[128][17];   // +1 pad: conflict-free transpose
    __shared__ __align__(16) float red[14][64][9];
    __shared__ __align__(16) float Wns[2048];
    __shared__ __align__(16) float Wms[2048];

    int tid = threadIdx.x;              // 0..1023
    int g0 = blockIdx.x * 16;
    int l = tid & 63, w = tid >> 6;     // wave 0..15
    int b = w >> 3, jq = w & 7;

    // issue adjacency-bit loads first (longest latency to LDS-ready)
    uint_t w0 = pk[g0 * 128 + tid];
    uint_t w1 = pk[g0 * 128 + 1024 + tid];

    // stage weights: 512 float4 each
    if (tid < 512) {
        ((float4*)Wns)[tid] = ((const float4*)Wn)[tid];
    } else {
        int t2 = tid - 512;
        ((float4*)Wms)[t2] = ((const float4*)Wm)[t2];
    }
    // stage ssrc (already pre-scaled): 8192 floats, 2 float4/thread
#pragma unroll
    for (int r = 0; r < 2; r++) {
        int idx = r * 4096 + tid * 4;
        int bb = idx >> 12, j = idx & 4095;
        *(float4*)&sm.ssm[bb][j] = *(const float4*)&ssrc[bb * G + j];
    }

    // per-wave stream setup + 4-deep hTb prefetch
    int m = l & 15, kg = l >> 4;
    int jstart = jq * 512;
    const ushort_t* hb0 = hTb_in + (size_t)(b * HID + m) * G + jstart + kg * 8;
    const ushort_t* hb1 = hb0 + (size_t)16 * G;
    short8 pb0[4], pb1[4];
#pragma unroll
    for (int d = 0; d < 4; d++) {
        pb0[d] = *(const short8*)(const void*)(hb0 + d * 32);
        pb1[d] = *(const short8*)(const void*)(hb1 + d * 32);
    }

    // LDS transpose of adjacency bits: word i = s*128+jw -> abits[jw][s]
    abits[tid & 127][tid >> 7] = w0;
    abits[tid & 127][(tid >> 7) + 8] = w1;

    float sd2 = sdst[b * G + g0 + m] + bep[0] * NLOG2E;
    const float wm1 = 1.f - coef;
    floatx4 c0 = {0.f, 0.f, 0.f, 0.f}, c1 = {0.f, 0.f, 0.f, 0.f};
    float es = 0.f;
    __syncthreads();

    const float* svp = &sm.ssm[b][jstart + kg * 8];
    const uint_t* abp = &abits[jq * 16][m];   // row stride 17
    float4 sv0[2], sv1[2];
    uint_t bwr[2];
#pragma unroll
    for (int d = 0; d < 2; d++) {
        sv0[d] = *(const float4*)&svp[d * 32];
        sv1[d] = *(const float4*)&svp[d * 32 + 4];
        bwr[d] = abp[d * 17];
    }

#pragma unroll
    for (int jc = 0; jc < 16; jc++) {   // FULL unroll: all indices static
        int pc = jc & 3, lc = jc & 1;
        short8 bf0 = pb0[pc], bf1 = pb1[pc];
        float4 s0 = sv0[lc], s1 = sv1[lc];
        uint_t bw = bwr[lc];
        if (jc + 4 < 16) {
            pb0[pc] = *(const short8*)(const void*)(hb0 + (jc + 4) * 32);
            pb1[pc] = *(const short8*)(const void*)(hb1 + (jc + 4) * 32);
        }
        if (jc + 2 < 16) {
            sv0[lc] = *(const float4*)&svp[(jc + 2) * 32];
            sv1[lc] = *(const float4*)&svp[(jc + 2) * 32 + 4];
            bwr[lc] = abp[(jc + 2) * 17];
        }
        float sv[8] = {s0.x, s0.y, s0.z, s0.w, s1.x, s1.y, s1.z, s1.w};
        short8 af;
#pragma unroll
        for (int t8 = 0; t8 < 8; t8++) {
            float bitf = (float)((bw >> (kg * 8 + t8)) & 1u);
            float wgt = __builtin_fmaf(bitf, wm1, coef);  // bit?1:coef
            float ex = exp2f(sd2 + sv[t8]);               // = exp(-logit)
            float e = __builtin_amdgcn_rcpf(1.f + ex) * wgt;
            es += e;
            af[t8] = (short)(__float_as_uint(e) >> 16);   // bf16 by truncation
        }
        c0 = __builtin_amdgcn_mfma_f32_16x16x32_bf16(af, bf0, c0, 0, 0, 0);
        c1 = __builtin_amdgcn_mfma_f32_16x16x32_bf16(af, bf1, c1, 0, 0, 0);
    }

    // 8-way jq merge
    if (jq) {
        int widx = b * 7 + jq - 1;
#pragma unroll
        for (int r = 0; r < 4; r++) {
            red[widx][l][r] = c0[r];
            red[widx][l][4 + r] = c1[r];
        }
        red[widx][l][8] = es;
    }
    __syncthreads();
    if (!jq) {
#pragma unroll
        for (int q = 0; q < 7; q++) {
            int widx = b * 7 + q;
#pragma unroll
            for (int r = 0; r < 4; r++) {
                c0[r] += red[widx][l][r];
                c1[r] += red[widx][l][4 + r];
            }
            es += red[widx][l][8];
        }
        es += __shfl_xor(es, 16);
        es += __shfl_xor(es, 32);
#pragma unroll
        for (int r = 0; r < 4; r++) {
            int gene = (l >> 4) * 4 + r;   // C/D: row=(l>>4)*4+reg, col=l&15
            sm.p.rec[gene * 2 + b][m] = c0[r];
            sm.p.rec[gene * 2 + b][16 + m] = c1[r];
        }
        if (l < 16) sm.p.esg[l][b] = es;
    }
    __syncthreads();

    // post: 32 rows x 32 cols = 1024 threads, single pass
    int rl = tid >> 5, hh = tid & 31;
    int gene = rl >> 1, bb = rl & 1;
    float xv = hin[((size_t)(bb * G + g0 + gene)) * HID + hh];
    sm.p.rec[rl][32 + hh] = xv * sm.p.esg[gene][bb];
    __syncthreads();

    float v = bnb[hh];
#pragma unroll
    for (int k4 = 0; k4 < 16; k4++) {
        float4 r4 = *(const float4*)&sm.p.rec[rl][k4 * 4];
        v += r4.x * Wns[(k4 * 4 + 0) * HID + hh];
        v += r4.y * Wns[(k4 * 4 + 1) * HID + hh];
        v += r4.z * Wns[(k4 * 4 + 2) * HID + hh];
        v += r4.w * Wns[(k4 * 4 + 3) * HID + hh];
    }
    v = elu1(v);
    sm.p.rec2[rl][hh] = v;
    sm.p.rec2[rl][32 + hh] = xv;
    // row handled by one half-wave: lockstep makes rec2 visible w/o barrier
    float u = bmb[hh];
#pragma unroll
    for (int k4 = 0; k4 < 16; k4++) {
        float4 r4 = *(const float4*)&sm.p.rec2[rl][k4 * 4];
        u += r4.x * Wms[(k4 * 4 + 0) * HID + hh];
        u += r4.y * Wms[(k4 * 4 + 1) * HID + hh];
        u += r4.z * Wms[(k4 * 4 + 2) * HID + hh];
        u += r4.w * Wms[(k4 * 4 + 3) * HID + hh];
    }
    float h1v = elu1(u);
    if (!DO_BN) {
        outp[((size_t)(bb * G + g0 + gene)) * HID + hh] = h1v;
    } else {
        // wave holds gene's full 64 values (lanes 0-31: b=0, 32-63: b=1)
        float s = h1v, sq = h1v * h1v;
#pragma unroll
        for (int mm = 32; mm; mm >>= 1) {
            s += __shfl_xor(s, mm);
            sq += __shfl_xor(sq, mm);
        }
        float mu = s * (1.f / 64.f);
        float var = sq * (1.f / 64.f) - mu * mu;
        float rstd = rsqrtf(var + 1e-5f);
        float hn = (h1v - mu) * rstd * gamma[g0 + gene] + beta[g0 + gene];
        outp[((size_t)(bb * G + g0 + gene)) * HID + hh] = hn;
        sm.p.tb[bb][hh][gene] = f2bf(hn);
        float ps = hn * We2[hh], pd = hn * We2[HID + hh];
#pragma unroll
        for (int mm = 16; mm; mm >>= 1) {
            ps += __shfl_xor(ps, mm);
            pd += __shfl_xor(pd, mm);
        }
        if (hh == 0) {
            s2s[bb * G + g0 + gene] = ps * NLOG2E;   // pre-scaled for layer 2
            s2d[bb * G + g0 + gene] = pd * NLOG2E;
        }
        __syncthreads();
        if (tid < 128) {
            int b2 = tid >> 6, c = (tid >> 1) & 31, half = tid & 1;
            short8 v8 = *(const short8*)&sm.p.tb[b2][c][half * 8];
            *(short8*)(void*)&hTb_out[(size_t)(b2 * HID + c) * G + g0 + half * 8] = v8;
        }
    }
}

extern "C" void kernel_launch(void* const* d_in, const int* in_sizes, int n_in,
                              void* d_out, int out_size, void* d_ws, size_t ws_size,
                              hipStream_t stream) {
    const float* x      = (const float*)d_in[0];
    const float* edges1 = (const float*)d_in[1];
    const float* edges2 = (const float*)d_in[2];
    const float* W_inf  = (const float*)d_in[3];
    const float* b_inf  = (const float*)d_in[4];
    const float* W_e1   = (const float*)d_in[5];
    const float* b_e1   = (const float*)d_in[6];
    const float* W_e2   = (const float*)d_in[7];
    const float* b_e2   = (const float*)d_in[8];
    const float* W_n1   = (const float*)d_in[9];
    const float* b_n1   = (const float*)d_in[10];
    const float* W_n2   = (const float*)d_in[11];
    const float* b_n2   = (const float*)d_in[12];
    const float* W_m1   = (const float*)d_in[13];
    const float* b_m1   = (const float*)d_in[14];
    const float* W_m2   = (const float*)d_in[15];
    const float* b_m2   = (const float*)d_in[16];
    const float* bn_g   = (const float*)d_in[17];
    const float* bn_b   = (const float*)d_in[18];
    float* out = (float*)d_out;

    float* ws = (float*)d_ws;
    float* h0   = ws;                           // 262144 floats
    float* h1n  = ws + 262144;                  // 262144
    float* s1s  = ws + 524288;                  // 8192
    float* s1d  = ws + 532480;                  // 8192
    float* s2s  = ws + 540672;                  // 8192
    float* s2d  = ws + 548864;                  // 8192
    ushort_t* hTb  = (ushort_t*)(ws + 557056);  // 262144 ushorts = 131072 floats
    ushort_t* hTb2 = (ushort_t*)(ws + 688128);  // 262144 ushorts
    uint_t* pk1 = (uint_t*)(ws + 819200);       // 524288 uints = 2 MB
    uint_t* pk2 = pk1 + 524288;                 // 2 MB
    // total ~ 7.3 MB

    const float ALPHA = 0.005f, BETA = 5e-5f;

    k_pre<<<4128, 256, 0, stream>>>(x, W_inf, b_inf, W_e1, h0, hTb, s1s, s1d,
                                    edges1, edges2, pk1, pk2);
    k_fused<true><<<G / 16, 1024, 0, stream>>>(
        pk1, s1s, s1d, hTb, b_e1, ALPHA, h0, W_n1, b_n1, W_m1, b_m1,
        bn_g, bn_b, W_e2, h1n, hTb2, s2s, s2d);
    k_fused<false><<<G / 16, 1024, 0, stream>>>(
        pk2, s2s, s2d, hTb2, b_e2, BETA, h1n, W_n2, b_n2, W_m2, b_m2,
        nullptr, nullptr, nullptr, out, nullptr, nullptr, nullptr);
}

// Round 8
// 253.662 us; speedup vs baseline: 1.0037x; 1.0037x over previous
//
#include <hip/hip_runtime.h>

#define G 4096
#define BSZ 2
#define NIN 8
#define HID 32
#define NLOG2E (-1.4426950408889634f)

typedef __attribute__((ext_vector_type(8))) short short8;
typedef __attribute__((ext_vector_type(4))) float floatx4;
typedef unsigned short ushort_t;
typedef unsigned int uint_t;

__device__ __forceinline__ float elu1(float v) {
    return v > 0.f ? v : (__expf(v) - 1.f);
}
__device__ __forceinline__ ushort_t f2bf(float f) {
    unsigned u = __float_as_uint(f);
    u += 0x7fffu + ((u >> 16) & 1u);
    return (ushort_t)(u >> 16);
}

// h = elu(x@W_infer+b); s_src/s_dst projections (PRE-SCALED by -log2e);
// hT bf16 [b][c][g] via LDS transpose.
__global__ __launch_bounds__(256) void k_setup1(
    const float* __restrict__ x, const float* __restrict__ W,
    const float* __restrict__ bias, const float* __restrict__ We,
    float* __restrict__ h0, ushort_t* __restrict__ hTb,
    float* __restrict__ ssrc, float* __restrict__ sdst) {
    __shared__ __align__(16) ushort_t hs[HID][264];
    int tid = threadIdx.x;
    int t = blockIdx.x * 256 + tid;
    int b = t >> 12;
    int g0 = (blockIdx.x & 15) * 256;
    float xin[NIN];
    const float* xp = x + t * NIN;
#pragma unroll
    for (int k = 0; k < NIN; k++) xin[k] = xp[k];
    float ss = 0.f, sd = 0.f;
    float* hp = h0 + (size_t)t * HID;
#pragma unroll
    for (int o = 0; o < HID; o++) {
        float v = bias[o];
#pragma unroll
        for (int k = 0; k < NIN; k++) v += xin[k] * W[k * HID + o];
        v = elu1(v);
        hp[o] = v;
        hs[o][tid] = f2bf(v);
        ss += v * We[o];
        sd += v * We[HID + o];
    }
    ssrc[t] = ss * NLOG2E;   // pre-scaled: consumer uses exp2f directly
    sdst[t] = sd * NLOG2E;
    __syncthreads();
#pragma unroll
    for (int p = 0; p < 4; p++) {
        int row = p * 8 + (tid >> 5);
        int c = (tid & 31) * 8;
        short8 v8 = *(const short8*)&hs[row][c];
        *(short8*)(void*)&hTb[(size_t)(b * HID + row) * G + g0 + c] = v8;
    }
}

// Fully fused MP block: 16 genes x 2 batches per block, full j-range.
// 512 threads = 8 waves (b x jq0..3), LDS 70 KB -> 2 BLOCKS/CU: one block's
// adjacency staging overlaps the other's compute (the structural fix for the
// ~60% stall time; 1024-thr/90KB forced 1 block/CU). In-register bit-pack
// staging (R0-proven pattern, 512-thr geometry); 32-iter main loop, 2-deep
// prefetch; 4-way jq merge; post phase in 2 passes of 16 rows.
template <bool DO_BN>
__global__ __launch_bounds__(512, 4) void k_fused(
    const float* __restrict__ adj, const float* __restrict__ ssrc,
    const float* __restrict__ sdst, const ushort_t* __restrict__ hTb_in,
    const float* __restrict__ bep, float coef, const float* __restrict__ hin,
    const float* __restrict__ Wn, const float* __restrict__ bnb,
    const float* __restrict__ Wm, const float* __restrict__ bmb,
    const float* __restrict__ gamma, const float* __restrict__ beta,
    const float* __restrict__ We2, float* __restrict__ outp,
    ushort_t* __restrict__ hTb_out, float* __restrict__ s2s,
    float* __restrict__ s2d) {
    union SMemU {
        float ssm[BSZ][G];                       // compute phase (32 KB)
        struct {                                 // post phase (~19.2 KB)
            float rec[32][68];
            float rec2[32][68];
            float esg[16][2];
            ushort_t tb[BSZ][HID][16];
        } p;
    };
    __shared__ __align__(16) SMemU sm;
    __shared__ __align__(16) uint_t abits[128][17];   // 8.7 KB (+1 pad)
    __shared__ __align__(16) float red[6][64][9];     // 13.8 KB
    __shared__ __align__(16) float Wns[2048];         // 8 KB
    __shared__ __align__(16) float Wms[2048];         // 8 KB
    // total ~70 KB -> 2 blocks/CU

    int tid = threadIdx.x;              // 0..511
    int g0 = blockIdx.x * 16;
    int l = tid & 63, w = tid >> 6;     // wave 0..7
    int b = w >> 2, jq = w & 3;

    // stage weights: 512 float4 each
    ((float4*)Wns)[tid] = ((const float4*)Wn)[tid];
    ((float4*)Wms)[tid] = ((const float4*)Wm)[tid];
    // stage ssrc (already pre-scaled): 8192 floats, 4 float4/thread
#pragma unroll
    for (int r = 0; r < 4; r++) {
        int idx = r * 2048 + tid * 4;
        int bb = idx >> 12, j = idx & 4095;
        *(float4*)&sm.ssm[bb][j] = *(const float4*)&ssrc[bb * G + j];
    }

    // per-wave stream setup + 2-deep hTb prefetch (issued before staging)
    int m = l & 15, kg = l >> 4;
    int jstart = jq * 1024;
    const ushort_t* hb0 = hTb_in + (size_t)(b * HID + m) * G + jstart + kg * 8;
    const ushort_t* hb1 = hb0 + (size_t)16 * G;
    short8 pb0[2], pb1[2];
#pragma unroll
    for (int d = 0; d < 2; d++) {
        pb0[d] = *(const short8*)(const void*)(hb0 + d * 32);
        pb1[d] = *(const short8*)(const void*)(hb1 + d * 32);
    }

    // stage adjacency bits: 8 batches x 2 rows; 4 float4 loads then 4 packs.
    // Row r, float4 f = h*512+tid -> word h*64+(tid>>3), bit (tid&7)*4+e.
    {
        const int sh2 = (tid & 7) * 4;
        const bool st = (tid & 7) == 0;
        const int wbase = tid >> 3;     // 0..63
        float4 ld[4];
#pragma unroll
        for (int bt = 0; bt < 8; bt++) {
            int r0 = bt * 2;
#pragma unroll
            for (int q = 0; q < 4; q++) {
                int r = r0 + (q >> 1), h = q & 1;
                ld[q] = *(const float4*)&adj[(size_t)(g0 + r) * G + (h * 512 + tid) * 4];
            }
#pragma unroll
            for (int q = 0; q < 4; q++) {
                int r = r0 + (q >> 1), h = q & 1;
                float4 v4 = ld[q];
                uint_t nib = (uint_t)(v4.x != 0.f) | ((uint_t)(v4.y != 0.f) << 1) |
                             ((uint_t)(v4.z != 0.f) << 2) | ((uint_t)(v4.w != 0.f) << 3);
                uint_t wd = nib << sh2;
                wd |= __shfl_xor(wd, 1);
                wd |= __shfl_xor(wd, 2);
                wd |= __shfl_xor(wd, 4);
                if (st) abits[h * 64 + wbase][r] = wd;
            }
        }
    }

    float sd2 = sdst[b * G + g0 + m] + bep[0] * NLOG2E;
    const float wm1 = 1.f - coef;
    floatx4 c0 = {0.f, 0.f, 0.f, 0.f}, c1 = {0.f, 0.f, 0.f, 0.f};
    float es = 0.f;
    __syncthreads();

    const float* svp = &sm.ssm[b][jstart + kg * 8];
    float4 sv0[2], sv1[2];
    uint_t bwr[2];
#pragma unroll
    for (int d = 0; d < 2; d++) {
        sv0[d] = *(const float4*)&svp[d * 32];
        sv1[d] = *(const float4*)&svp[d * 32 + 4];
        bwr[d] = abits[jq * 32 + d][m];
    }

#pragma unroll 4
    for (int jc = 0; jc < 32; jc++) {
        int lc = jc & 1;
        short8 bf0 = pb0[lc], bf1 = pb1[lc];
        float4 s0 = sv0[lc], s1 = sv1[lc];
        uint_t bw = bwr[lc];
        if (jc + 2 < 32) {
            pb0[lc] = *(const short8*)(const void*)(hb0 + (jc + 2) * 32);
            pb1[lc] = *(const short8*)(const void*)(hb1 + (jc + 2) * 32);
            sv0[lc] = *(const float4*)&svp[(jc + 2) * 32];
            sv1[lc] = *(const float4*)&svp[(jc + 2) * 32 + 4];
            bwr[lc] = abits[jq * 32 + jc + 2][m];
        }
        float sv[8] = {s0.x, s0.y, s0.z, s0.w, s1.x, s1.y, s1.z, s1.w};
        short8 af;
#pragma unroll
        for (int t8 = 0; t8 < 8; t8++) {
            float bitf = (float)((bw >> (kg * 8 + t8)) & 1u);
            float wgt = __builtin_fmaf(bitf, wm1, coef);  // bit?1:coef
            float ex = exp2f(sd2 + sv[t8]);               // = exp(-logit)
            float e = __builtin_amdgcn_rcpf(1.f + ex) * wgt;
            es += e;
            af[t8] = (short)(__float_as_uint(e) >> 16);   // bf16 by truncation
        }
        c0 = __builtin_amdgcn_mfma_f32_16x16x32_bf16(af, bf0, c0, 0, 0, 0);
        c1 = __builtin_amdgcn_mfma_f32_16x16x32_bf16(af, bf1, c1, 0, 0, 0);
    }

    // 4-way jq merge
    if (jq) {
        int widx = b * 3 + jq - 1;
#pragma unroll
        for (int r = 0; r < 4; r++) {
            red[widx][l][r] = c0[r];
            red[widx][l][4 + r] = c1[r];
        }
        red[widx][l][8] = es;
    }
    __syncthreads();
    if (!jq) {
#pragma unroll
        for (int q = 0; q < 3; q++) {
            int widx = b * 3 + q;
#pragma unroll
            for (int r = 0; r < 4; r++) {
                c0[r] += red[widx][l][r];
                c1[r] += red[widx][l][4 + r];
            }
            es += red[widx][l][8];
        }
        es += __shfl_xor(es, 16);
        es += __shfl_xor(es, 32);
#pragma unroll
        for (int r = 0; r < 4; r++) {
            int gene = (l >> 4) * 4 + r;   // C/D: row=(l>>4)*4+reg, col=l&15
            sm.p.rec[gene * 2 + b][m] = c0[r];
            sm.p.rec[gene * 2 + b][16 + m] = c1[r];
        }
        if (l < 16) sm.p.esg[l][b] = es;
    }
    __syncthreads();

    // post: 32 rows x 32 cols, 512 threads -> 2 passes of 16 rows
    int rl = tid >> 5, hh = tid & 31;
    float xv[2];
#pragma unroll
    for (int p = 0; p < 2; p++) {
        int rr = rl + p * 16, gene = rr >> 1, bb = rr & 1;
        xv[p] = hin[((size_t)(bb * G + g0 + gene)) * HID + hh];
        sm.p.rec[rr][32 + hh] = xv[p] * sm.p.esg[gene][bb];
    }
    __syncthreads();

#pragma unroll
    for (int p = 0; p < 2; p++) {
        int rr = rl + p * 16, gene = rr >> 1, bb = rr & 1;
        float v = bnb[hh];
#pragma unroll
        for (int k4 = 0; k4 < 16; k4++) {
            float4 r4 = *(const float4*)&sm.p.rec[rr][k4 * 4];
            v += r4.x * Wns[(k4 * 4 + 0) * HID + hh];
            v += r4.y * Wns[(k4 * 4 + 1) * HID + hh];
            v += r4.z * Wns[(k4 * 4 + 2) * HID + hh];
            v += r4.w * Wns[(k4 * 4 + 3) * HID + hh];
        }
        v = elu1(v);
        sm.p.rec2[rr][hh] = v;
        sm.p.rec2[rr][32 + hh] = xv[p];
        // row handled by one half-wave: lockstep makes rec2 visible w/o barrier
        float u = bmb[hh];
#pragma unroll
        for (int k4 = 0; k4 < 16; k4++) {
            float4 r4 = *(const float4*)&sm.p.rec2[rr][k4 * 4];
            u += r4.x * Wms[(k4 * 4 + 0) * HID + hh];
            u += r4.y * Wms[(k4 * 4 + 1) * HID + hh];
            u += r4.z * Wms[(k4 * 4 + 2) * HID + hh];
            u += r4.w * Wms[(k4 * 4 + 3) * HID + hh];
        }
        float h1v = elu1(u);
        if (!DO_BN) {
            outp[((size_t)(bb * G + g0 + gene)) * HID + hh] = h1v;
        } else {
            // wave holds gene's full 64 values (lanes 0-31: b=0, 32-63: b=1)
            float s = h1v, sq = h1v * h1v;
#pragma unroll
            for (int mm = 32; mm; mm >>= 1) {
                s += __shfl_xor(s, mm);
                sq += __shfl_xor(sq, mm);
            }
            float mu = s * (1.f / 64.f);
            float var = sq * (1.f / 64.f) - mu * mu;
            float rstd = rsqrtf(var + 1e-5f);
            float hn = (h1v - mu) * rstd * gamma[g0 + gene] + beta[g0 + gene];
            outp[((size_t)(bb * G + g0 + gene)) * HID + hh] = hn;
            sm.p.tb[bb][hh][gene] = f2bf(hn);
            float ps = hn * We2[hh], pd = hn * We2[HID + hh];
#pragma unroll
            for (int mm = 16; mm; mm >>= 1) {
                ps += __shfl_xor(ps, mm);
                pd += __shfl_xor(pd, mm);
            }
            if (hh == 0) {
                s2s[bb * G + g0 + gene] = ps * NLOG2E;   // pre-scaled for layer 2
                s2d[bb * G + g0 + gene] = pd * NLOG2E;
            }
        }
    }
    if (DO_BN) {
        __syncthreads();
        if (tid < 128) {
            int b2 = tid >> 6, c = (tid >> 1) & 31, half = tid & 1;
            short8 v8 = *(const short8*)&sm.p.tb[b2][c][half * 8];
            *(short8*)(void*)&hTb_out[(size_t)(b2 * HID + c) * G + g0 + half * 8] = v8;
        }
    }
}

extern "C" void kernel_launch(void* const* d_in, const int* in_sizes, int n_in,
                              void* d_out, int out_size, void* d_ws, size_t ws_size,
                              hipStream_t stream) {
    const float* x      = (const float*)d_in[0];
    const float* edges1 = (const float*)d_in[1];
    const float* edges2 = (const float*)d_in[2];
    const float* W_inf  = (const float*)d_in[3];
    const float* b_inf  = (const float*)d_in[4];
    const float* W_e1   = (const float*)d_in[5];
    const float* b_e1   = (const float*)d_in[6];
    const float* W_e2   = (const float*)d_in[7];
    const float* b_e2   = (const float*)d_in[8];
    const float* W_n1   = (const float*)d_in[9];
    const float* b_n1   = (const float*)d_in[10];
    const float* W_n2   = (const float*)d_in[11];
    const float* b_n2   = (const float*)d_in[12];
    const float* W_m1   = (const float*)d_in[13];
    const float* b_m1   = (const float*)d_in[14];
    const float* W_m2   = (const float*)d_in[15];
    const float* b_m2   = (const float*)d_in[16];
    const float* bn_g   = (const float*)d_in[17];
    const float* bn_b   = (const float*)d_in[18];
    float* out = (float*)d_out;

    float* ws = (float*)d_ws;
    float* h0   = ws;                           // 262144 floats
    float* h1n  = ws + 262144;                  // 262144
    float* s1s  = ws + 524288;                  // 8192
    float* s1d  = ws + 532480;                  // 8192
    float* s2s  = ws + 540672;                  // 8192
    float* s2d  = ws + 548864;                  // 8192
    ushort_t* hTb  = (ushort_t*)(ws + 557056);  // 262144 ushorts = 131072 floats
    ushort_t* hTb2 = (ushort_t*)(ws + 688128);  // 262144 ushorts
    // total ~ 819200 floats = 3.3 MB

    const float ALPHA = 0.005f, BETA = 5e-5f;

    k_setup1<<<32, 256, 0, stream>>>(x, W_inf, b_inf, W_e1, h0, hTb, s1s, s1d);
    k_fused<true><<<G / 16, 512, 0, stream>>>(
        edges1, s1s, s1d, hTb, b_e1, ALPHA, h0, W_n1, b_n1, W_m1, b_m1,
        bn_g, bn_b, W_e2, h1n, hTb2, s2s, s2d);
    k_fused<false><<<G / 16, 512, 0, stream>>>(
        edges2, s2s, s2d, hTb2, b_e2, BETA, h1n, W_n2, b_n2, W_m2, b_m2,
        nullptr, nullptr, nullptr, out, nullptr, nullptr, nullptr);
}

// Round 9
// 229.653 us; speedup vs baseline: 1.1087x; 1.1045x over previous
//
#include <hip/hip_runtime.h>

#define G 4096
#define BSZ 2
#define NIN 8
#define HID 32
#define NLOG2E (-1.4426950408889634f)

typedef __attribute__((ext_vector_type(8))) short short8;
typedef __attribute__((ext_vector_type(4))) float floatx4;
typedef unsigned short ushort_t;
typedef unsigned int uint_t;

__device__ __forceinline__ float elu1(float v) {
    return v > 0.f ? v : (__expf(v) - 1.f);
}
__device__ __forceinline__ ushort_t f2bf(float f) {
    unsigned u = __float_as_uint(f);
    u += 0x7fffu + ((u >> 16) & 1u);
    return (ushort_t)(u >> 16);
}

// h = elu(x@W_infer+b); s_src/s_dst projections (PRE-SCALED by -log2e);
// hT bf16 [b][c][g] via LDS transpose.
__global__ __launch_bounds__(256) void k_setup1(
    const float* __restrict__ x, const float* __restrict__ W,
    const float* __restrict__ bias, const float* __restrict__ We,
    float* __restrict__ h0, ushort_t* __restrict__ hTb,
    float* __restrict__ ssrc, float* __restrict__ sdst) {
    __shared__ __align__(16) ushort_t hs[HID][264];
    int tid = threadIdx.x;
    int t = blockIdx.x * 256 + tid;
    int b = t >> 12;
    int g0 = (blockIdx.x & 15) * 256;
    float xin[NIN];
    const float* xp = x + t * NIN;
#pragma unroll
    for (int k = 0; k < NIN; k++) xin[k] = xp[k];
    float ss = 0.f, sd = 0.f;
    float* hp = h0 + (size_t)t * HID;
#pragma unroll
    for (int o = 0; o < HID; o++) {
        float v = bias[o];
#pragma unroll
        for (int k = 0; k < NIN; k++) v += xin[k] * W[k * HID + o];
        v = elu1(v);
        hp[o] = v;
        hs[o][tid] = f2bf(v);
        ss += v * We[o];
        sd += v * We[HID + o];
    }
    ssrc[t] = ss * NLOG2E;   // pre-scaled: consumer uses exp2f directly
    sdst[t] = sd * NLOG2E;
    __syncthreads();
#pragma unroll
    for (int p = 0; p < 4; p++) {
        int row = p * 8 + (tid >> 5);
        int c = (tid & 31) * 8;
        short8 v8 = *(const short8*)&hs[row][c];
        *(short8*)(void*)&hTb[(size_t)(b * HID + row) * G + g0 + c] = v8;
    }
}

// Partial message-passing: grid 1024 = 256 gene-blocks x 4 j-quarters.
// 512 threads = 8 waves (b x jq0..3); per block: stage 16x1024 adjacency
// (bit-pack) + ssm quarter; 8-iter MFMA loop (verified R8 body); 4-way jq
// merge; write rec[32][32]+es[32] partials to ws. Small LDS (24.7 KB) and
// grid >> CUs give multi-block-per-CU overlap of staging and compute.
__global__ __launch_bounds__(512, 2) void k_mp(
    const float* __restrict__ adj, const float* __restrict__ ssrc,
    const float* __restrict__ sdst, const ushort_t* __restrict__ hTb_in,
    const float* __restrict__ bep, float coef, float* __restrict__ pr) {
    __shared__ __align__(16) float ssm[BSZ][1024];    // 8 KB
    __shared__ __align__(16) uint_t abits[32][17];    // 2.2 KB
    __shared__ __align__(16) float red[6][64][9];     // 13.8 KB

    int tid = threadIdx.x;              // 0..511
    int gblk = blockIdx.x >> 2, jh = blockIdx.x & 3;
    int g0 = gblk * 16, j0 = jh * 1024;
    int l = tid & 63, w = tid >> 6;     // wave 0..7
    int b = w >> 2, jq = w & 3;
    int m = l & 15, kg = l >> 4;

    // hTb prefetch first (longest dependency to first MFMA)
    int jstart = j0 + jq * 256;
    const ushort_t* hb0 = hTb_in + (size_t)(b * HID + m) * G + jstart + kg * 8;
    const ushort_t* hb1 = hb0 + (size_t)16 * G;
    short8 pb0[2], pb1[2];
#pragma unroll
    for (int d = 0; d < 2; d++) {
        pb0[d] = *(const short8*)(const void*)(hb0 + d * 32);
        pb1[d] = *(const short8*)(const void*)(hb1 + d * 32);
    }

    // stage ssm quarter: 1 float4/thread
    {
        int bb = tid >> 8, j4 = tid & 255;
        *(float4*)&ssm[bb][j4 * 4] = *(const float4*)&ssrc[bb * G + j0 + j4 * 4];
    }
    // stage adjacency bits: 8 rounds x 2 rows (R0-style, 1 float4 live)
    {
        int r = tid >> 8, f4 = tid & 255;
        int word = f4 >> 3;
        int sh2 = (tid & 7) * 4;
        bool st = (tid & 7) == 0;
#pragma unroll
        for (int rr = 0; rr < 8; rr++) {
            float4 v4 = *(const float4*)&adj[(size_t)(g0 + rr * 2 + r) * G + j0 + f4 * 4];
            uint_t nib = (uint_t)(v4.x != 0.f) | ((uint_t)(v4.y != 0.f) << 1) |
                         ((uint_t)(v4.z != 0.f) << 2) | ((uint_t)(v4.w != 0.f) << 3);
            uint_t wd = nib << sh2;
            wd |= __shfl_xor(wd, 1);
            wd |= __shfl_xor(wd, 2);
            wd |= __shfl_xor(wd, 4);
            if (st) abits[word][rr * 2 + r] = wd;
        }
    }

    float sd2 = sdst[b * G + g0 + m] + bep[0] * NLOG2E;
    const float wm1 = 1.f - coef;
    floatx4 c0 = {0.f, 0.f, 0.f, 0.f}, c1 = {0.f, 0.f, 0.f, 0.f};
    float es = 0.f;
    __syncthreads();

    const float* svp = &ssm[b][jq * 256 + kg * 8];
    float4 sv0[2], sv1[2];
    uint_t bwr[2];
#pragma unroll
    for (int d = 0; d < 2; d++) {
        sv0[d] = *(const float4*)&svp[d * 32];
        sv1[d] = *(const float4*)&svp[d * 32 + 4];
        bwr[d] = abits[jq * 8 + d][m];
    }

#pragma unroll
    for (int jc = 0; jc < 8; jc++) {
        int lc = jc & 1;
        short8 bf0 = pb0[lc], bf1 = pb1[lc];
        float4 s0 = sv0[lc], s1 = sv1[lc];
        uint_t bw = bwr[lc];
        if (jc + 2 < 8) {
            pb0[lc] = *(const short8*)(const void*)(hb0 + (jc + 2) * 32);
            pb1[lc] = *(const short8*)(const void*)(hb1 + (jc + 2) * 32);
            sv0[lc] = *(const float4*)&svp[(jc + 2) * 32];
            sv1[lc] = *(const float4*)&svp[(jc + 2) * 32 + 4];
            bwr[lc] = abits[jq * 8 + jc + 2][m];
        }
        float sv[8] = {s0.x, s0.y, s0.z, s0.w, s1.x, s1.y, s1.z, s1.w};
        short8 af;
#pragma unroll
        for (int t8 = 0; t8 < 8; t8++) {
            float bitf = (float)((bw >> (kg * 8 + t8)) & 1u);
            float wgt = __builtin_fmaf(bitf, wm1, coef);  // bit?1:coef
            float ex = exp2f(sd2 + sv[t8]);               // = exp(-logit)
            float e = __builtin_amdgcn_rcpf(1.f + ex) * wgt;
            es += e;
            af[t8] = (short)(__float_as_uint(e) >> 16);   // bf16 by truncation
        }
        c0 = __builtin_amdgcn_mfma_f32_16x16x32_bf16(af, bf0, c0, 0, 0, 0);
        c1 = __builtin_amdgcn_mfma_f32_16x16x32_bf16(af, bf1, c1, 0, 0, 0);
    }

    // 4-way jq merge
    if (jq) {
        int widx = b * 3 + jq - 1;
#pragma unroll
        for (int r = 0; r < 4; r++) {
            red[widx][l][r] = c0[r];
            red[widx][l][4 + r] = c1[r];
        }
        red[widx][l][8] = es;
    }
    __syncthreads();
    if (!jq) {
#pragma unroll
        for (int q = 0; q < 3; q++) {
            int widx = b * 3 + q;
#pragma unroll
            for (int r = 0; r < 4; r++) {
                c0[r] += red[widx][l][r];
                c1[r] += red[widx][l][4 + r];
            }
            es += red[widx][l][8];
        }
        es += __shfl_xor(es, 16);
        es += __shfl_xor(es, 32);
        float* prb = pr + (size_t)blockIdx.x * 1056;
#pragma unroll
        for (int r = 0; r < 4; r++) {
            int gene = (l >> 4) * 4 + r;   // C/D: row=(l>>4)*4+reg, col=l&15
            int row = gene * 2 + b;
            prb[row * 32 + m] = c0[r];
            prb[row * 32 + 16 + m] = c1[r];
        }
        if (l < 16) prb[1024 + l * 2 + b] = es;
    }
}

// Combine 4 j-quarter partials + node/merge MLP (+BN+proj+hT for layer 1).
// Grid 256 x 1024 threads; post phase identical to the verified R0 tail.
template <bool DO_BN>
__global__ __launch_bounds__(1024, 4) void k_post(
    const float* __restrict__ pr, const float* __restrict__ hin,
    const float* __restrict__ Wn, const float* __restrict__ bnb,
    const float* __restrict__ Wm, const float* __restrict__ bmb,
    const float* __restrict__ gamma, const float* __restrict__ beta,
    const float* __restrict__ We2, float* __restrict__ outp,
    ushort_t* __restrict__ hTb_out, float* __restrict__ s2s,
    float* __restrict__ s2d) {
    __shared__ __align__(16) float rec[32][68];
    __shared__ __align__(16) float rec2[32][68];
    __shared__ __align__(16) ushort_t tb[BSZ][HID][16];
    __shared__ __align__(16) float Wns[2048];
    __shared__ __align__(16) float Wms[2048];

    int tid = threadIdx.x;
    int g0 = blockIdx.x * 16;
    if (tid < 512) {
        ((float4*)Wns)[tid] = ((const float4*)Wn)[tid];
    } else {
        ((float4*)Wms)[tid - 512] = ((const float4*)Wm)[tid - 512];
    }
    int rl = tid >> 5, hh = tid & 31;
    int gene = rl >> 1, bb = rl & 1;
    const float* p0 = pr + (size_t)blockIdx.x * 4 * 1056;
    float rv = p0[rl * 32 + hh] + p0[1056 + rl * 32 + hh] +
               p0[2112 + rl * 32 + hh] + p0[3168 + rl * 32 + hh];
    float esv = p0[1024 + rl] + p0[1056 + 1024 + rl] +
                p0[2112 + 1024 + rl] + p0[3168 + 1024 + rl];
    float xv = hin[((size_t)(bb * G + g0 + gene)) * HID + hh];
    rec[rl][hh] = rv;
    rec[rl][32 + hh] = xv * esv;
    __syncthreads();

    float v = bnb[hh];
#pragma unroll
    for (int k4 = 0; k4 < 16; k4++) {
        float4 r4 = *(const float4*)&rec[rl][k4 * 4];
        v += r4.x * Wns[(k4 * 4 + 0) * HID + hh];
        v += r4.y * Wns[(k4 * 4 + 1) * HID + hh];
        v += r4.z * Wns[(k4 * 4 + 2) * HID + hh];
        v += r4.w * Wns[(k4 * 4 + 3) * HID + hh];
    }
    v = elu1(v);
    rec2[rl][hh] = v;
    rec2[rl][32 + hh] = xv;
    // row handled by one half-wave: lockstep makes rec2 visible w/o barrier
    float u = bmb[hh];
#pragma unroll
    for (int k4 = 0; k4 < 16; k4++) {
        float4 r4 = *(const float4*)&rec2[rl][k4 * 4];
        u += r4.x * Wms[(k4 * 4 + 0) * HID + hh];
        u += r4.y * Wms[(k4 * 4 + 1) * HID + hh];
        u += r4.z * Wms[(k4 * 4 + 2) * HID + hh];
        u += r4.w * Wms[(k4 * 4 + 3) * HID + hh];
    }
    float h1v = elu1(u);
    if (!DO_BN) {
        outp[((size_t)(bb * G + g0 + gene)) * HID + hh] = h1v;
    } else {
        // wave holds gene's full 64 values (lanes 0-31: b=0, 32-63: b=1)
        float s = h1v, sq = h1v * h1v;
#pragma unroll
        for (int mm = 32; mm; mm >>= 1) {
            s += __shfl_xor(s, mm);
            sq += __shfl_xor(sq, mm);
        }
        float mu = s * (1.f / 64.f);
        float var = sq * (1.f / 64.f) - mu * mu;
        float rstd = rsqrtf(var + 1e-5f);
        float hn = (h1v - mu) * rstd * gamma[g0 + gene] + beta[g0 + gene];
        outp[((size_t)(bb * G + g0 + gene)) * HID + hh] = hn;
        tb[bb][hh][gene] = f2bf(hn);
        float ps = hn * We2[hh], pd = hn * We2[HID + hh];
#pragma unroll
        for (int mm = 16; mm; mm >>= 1) {
            ps += __shfl_xor(ps, mm);
            pd += __shfl_xor(pd, mm);
        }
        if (hh == 0) {
            s2s[bb * G + g0 + gene] = ps * NLOG2E;   // pre-scaled for layer 2
            s2d[bb * G + g0 + gene] = pd * NLOG2E;
        }
        __syncthreads();
        if (tid < 128) {
            int b2 = tid >> 6, c = (tid >> 1) & 31, half = tid & 1;
            short8 v8 = *(const short8*)&tb[b2][c][half * 8];
            *(short8*)(void*)&hTb_out[(size_t)(b2 * HID + c) * G + g0 + half * 8] = v8;
        }
    }
}

extern "C" void kernel_launch(void* const* d_in, const int* in_sizes, int n_in,
                              void* d_out, int out_size, void* d_ws, size_t ws_size,
                              hipStream_t stream) {
    const float* x      = (const float*)d_in[0];
    const float* edges1 = (const float*)d_in[1];
    const float* edges2 = (const float*)d_in[2];
    const float* W_inf  = (const float*)d_in[3];
    const float* b_inf  = (const float*)d_in[4];
    const float* W_e1   = (const float*)d_in[5];
    const float* b_e1   = (const float*)d_in[6];
    const float* W_e2   = (const float*)d_in[7];
    const float* b_e2   = (const float*)d_in[8];
    const float* W_n1   = (const float*)d_in[9];
    const float* b_n1   = (const float*)d_in[10];
    const float* W_n2   = (const float*)d_in[11];
    const float* b_n2   = (const float*)d_in[12];
    const float* W_m1   = (const float*)d_in[13];
    const float* b_m1   = (const float*)d_in[14];
    const float* W_m2   = (const float*)d_in[15];
    const float* b_m2   = (const float*)d_in[16];
    const float* bn_g   = (const float*)d_in[17];
    const float* bn_b   = (const float*)d_in[18];
    float* out = (float*)d_out;

    float* ws = (float*)d_ws;
    float* h0   = ws;                           // 262144 floats
    float* h1n  = ws + 262144;                  // 262144
    float* s1s  = ws + 524288;                  // 8192
    float* s1d  = ws + 532480;                  // 8192
    float* s2s  = ws + 540672;                  // 8192
    float* s2d  = ws + 548864;                  // 8192
    ushort_t* hTb  = (ushort_t*)(ws + 557056);  // 262144 ushorts = 131072 floats
    ushort_t* hTb2 = (ushort_t*)(ws + 688128);  // 262144 ushorts
    float* pr = ws + 819200;                    // 1024*1056 = 1081344 floats
    // total ~ 1900544 floats = 7.6 MB

    const float ALPHA = 0.005f, BETA = 5e-5f;

    k_setup1<<<32, 256, 0, stream>>>(x, W_inf, b_inf, W_e1, h0, hTb, s1s, s1d);
    k_mp<<<1024, 512, 0, stream>>>(edges1, s1s, s1d, hTb, b_e1, ALPHA, pr);
    k_post<true><<<256, 1024, 0, stream>>>(
        pr, h0, W_n1, b_n1, W_m1, b_m1, bn_g, bn_b, W_e2,
        h1n, hTb2, s2s, s2d);
    k_mp<<<1024, 512, 0, stream>>>(edges2, s2s, s2d, hTb2, b_e2, BETA, pr);
    k_post<false><<<256, 1024, 0, stream>>>(
        pr, h1n, W_n2, b_n2, W_m2, b_m2, nullptr, nullptr, nullptr,
        out, nullptr, nullptr, nullptr);
}